// Round 2
// baseline (201318.530 us; speedup 1.0000x reference)
//
#include <hip/hip_runtime.h>
#include <stdint.h>

// RNN-T greedy decode, fp32 storage / fp64 accumulate, persistent-kernel design.
// v2: all scratch in __device__ globals (no ws_size dependence); plain launch
// (no cooperative API) with occupancy-guaranteed co-residency of 448 blocks.
//
// Per sym step (5000 total, strictly sequential):
//   gate blocks : gates = G_cur + LUT[last]; pointwise -> h_new (publish, F1)
//                 then speculative G_spec = h_new @ Wh (overlaps joint path)
//   pred blocks : tanhvec = tanh(encT[t] + h_new @ Wpred)  (F2)
//   out  blocks : logits cols + per-block argmax candidates (F3)
//   argmax blks : per-row reduce 129 candidates -> sym/emit/last (F4)
//   gate blocks : on emit commit G_spec/c/h
// h_new double-buffered by step parity (WAR across steps).

typedef unsigned int u32;

constexpr int NGB = 160, NPB = 160, NOB = 128, NBLK = NGB + NPB + NOB; // 448
constexpr int LDSTR = 648; // padded LDS row stride (2-way bank alias only = free)

// ---- static device scratch (~93 MB total; allocated at module load) ----
__device__ float  g_encT[1000 * 32 * 640];   // enc@Wenc + b_joint, [T][B][J]
__device__ float  g_lut[1025 * 2560];        // embed@Wx + b_lstm (row 1024 = b_lstm)
__device__ float  g_hnew[2 * 32 * 640];      // double-buffered by step parity
__device__ float  g_tnh[32 * 640];           // tanh(joint pre-act)
__device__ double g_cval[32 * 132];          // argmax candidate values
__device__ int    g_cidx[32 * 132];          // argmax candidate indices
__device__ int    g_last[32];
__device__ int    g_emit[32];
__device__ u32    g_cnt[64 * 32];            // counters, 128 B apart

// counter slot indices (each slot = 32 u32 = 128 B)
constexpr int F1L = 0,  F1R = 10;  // 10 leaves x16 gate blocks
constexpr int F2L = 11, F2R = 21;  // 10 leaves x16 pred blocks
constexpr int F3L = 22, F3R = 30;  // 8 leaves x16 out blocks + 1 direct (9/step)
constexpr int F4L = 31, F4R = 33;  // 2 leaves x16 argmax blocks

__device__ __forceinline__ float sigmf(float x) { return 1.0f / (1.0f + expf(-x)); }

__device__ __forceinline__ void bump(int leaf, int root, int step) {
  // caller: thread 0, after __syncthreads() (all waves' stores vmcnt-drained)
  __builtin_amdgcn_fence(__ATOMIC_RELEASE, "agent");
  u32 old = __hip_atomic_fetch_add(&g_cnt[leaf * 32], 1u, __ATOMIC_RELAXED, __HIP_MEMORY_SCOPE_AGENT);
  if (old + 1u == (u32)(step + 1) * 16u)
    __hip_atomic_fetch_add(&g_cnt[root * 32], 1u, __ATOMIC_RELAXED, __HIP_MEMORY_SCOPE_AGENT);
}

__device__ __forceinline__ void waitc(int root, u32 target) {
  if (threadIdx.x == 0) {
    while (__hip_atomic_load(&g_cnt[root * 32], __ATOMIC_RELAXED, __HIP_MEMORY_SCOPE_AGENT) < target)
      __builtin_amdgcn_s_sleep(1);
    __builtin_amdgcn_fence(__ATOMIC_ACQUIRE, "agent");  // invalidate stale cache lines
  }
  __syncthreads();
}

// ---------------- precompute: LUT = embed @ Wx + b_lstm (row 1024 = b_lstm) -----------
__global__ __launch_bounds__(256) void k_lut(const float* __restrict__ embed,
                                             const float* __restrict__ Wx,
                                             const float* __restrict__ b_lstm) {
  const int tid = threadIdx.x;
  const int cg = blockIdx.x % 10, rg = blockIdx.x / 10;  // rg 0..128
  const int c = cg * 256 + tid;
  const int r0 = rg * 8;
  double acc[8];
  double bl = (double)b_lstm[c];
#pragma unroll
  for (int i = 0; i < 8; i++) acc[i] = bl;
  for (int e = 0; e < 640; e++) {
    double wx = (double)Wx[(size_t)e * 2560 + c];
#pragma unroll
    for (int i = 0; i < 8; i++) {
      int r = r0 + i;
      if (r < 1024) acc[i] += (double)embed[(size_t)r * 640 + e] * wx;
    }
  }
#pragma unroll
  for (int i = 0; i < 8; i++) {
    int r = r0 + i;
    if (r < 1025) g_lut[(size_t)r * 2560 + c] = (float)acc[i];
  }
  if (blockIdx.x == 0) {  // init counters / last / emit every call
    for (int i = tid; i < 64 * 32; i += 256) g_cnt[i] = 0u;
    if (tid < 32) { g_last[tid] = 1024; g_emit[tid] = 0; }
  }
}

// ------------- precompute: encT[t][b][j] = sum_d enc[b][d][t]*Wenc[d][j] + b_joint[j] --
__global__ __launch_bounds__(256) void k_encproj(const float* __restrict__ enc,
                                                 const float* __restrict__ Wenc,
                                                 const float* __restrict__ bj) {
  __shared__ __align__(16) float As[16][68];
  __shared__ __align__(16) float Bs[16][68];
  const int tid = threadIdx.x;
  const int jt = blockIdx.x % 10, tt = blockIdx.x / 10;  // 10 j-tiles, 16 t-tiles
  const int b = blockIdx.y;
  const int t0 = tt * 64, j0 = jt * 64;
  const int ty = tid >> 4, tx = tid & 15;
  double acc[4][4] = {};
  const float* Ab = enc + (size_t)b * 640 * 1000;
  for (int d0 = 0; d0 < 640; d0 += 16) {
#pragma unroll
    for (int i = 0; i < 4; i++) {
      int idx = tid + i * 256;
      int d = idx >> 6, t = idx & 63;
      As[d][t] = (t0 + t < 1000) ? Ab[(size_t)(d0 + d) * 1000 + t0 + t] : 0.f;
      Bs[d][t] = Wenc[(size_t)(d0 + d) * 640 + j0 + t];
    }
    __syncthreads();
#pragma unroll
    for (int kk = 0; kk < 16; kk++) {
      float4 av = *(const float4*)&As[kk][ty * 4];
      float4 bv = *(const float4*)&Bs[kk][tx * 4];
      float a[4] = {av.x, av.y, av.z, av.w};
      float bb[4] = {bv.x, bv.y, bv.z, bv.w};
#pragma unroll
      for (int i = 0; i < 4; i++)
#pragma unroll
        for (int j = 0; j < 4; j++) acc[i][j] += (double)a[i] * (double)bb[j];
    }
    __syncthreads();
  }
#pragma unroll
  for (int i = 0; i < 4; i++) {
    int t = t0 + ty * 4 + i;
    if (t < 1000)
#pragma unroll
      for (int j = 0; j < 4; j++)
        g_encT[(size_t)t * 20480 + b * 640 + j0 + tx * 4 + j] =
            (float)(acc[i][j] + (double)bj[j0 + tx * 4 + j]);
  }
}

// ------------------------------- persistent decode ------------------------------------
__global__ __launch_bounds__(256, 2) void k_decode(float* __restrict__ out,
                                                   const int* __restrict__ lens,
                                                   const float* __restrict__ Wh,
                                                   const float* __restrict__ Wpred,
                                                   const float* __restrict__ Wout,
                                                   const float* __restrict__ b_out) {
  __shared__ __align__(16) float wsl[16 * LDSTR];  // weight slice (role-dependent)
  __shared__ double sval[256];
  __shared__ int sidx[256];

  const int tid = threadIdx.x;
  const int bid = blockIdx.x;

  if (bid < NGB) {
    // ================= GATE role: 4 units each; 16 Wh cols in LDS ==================
    const int b = tid >> 3, c0 = tid & 7;
    const int u0 = bid * 4;
    for (int idx = tid; idx < 16 * 640; idx += 256) {
      int ci = idx / 640, k = idx - ci * 640;
      int g = ci >> 2, ul = ci & 3;
      wsl[ci * LDSTR + k] = Wh[(size_t)k * 2560 + g * 640 + u0 + ul];
    }
    __syncthreads();
    // thread (b,c0): gate cols ci=c0 (g=c0>>2 in {i,f}) and ci=c0+8 (g+2 in {g,o})
    const int g1 = c0 >> 2, ul = c0 & 3;
    const int col1 = g1 * 640 + u0 + ul;
    const int col2 = col1 + 1280;
    double G1 = 0.0, G2 = 0.0, ccur = 0.0;  // invariant: G = h_committed @ Wh
    float hcur = 0.f;
    const float* w1 = &wsl[c0 * LDSTR];
    const float* w2 = &wsl[(c0 + 8) * LDSTR];

    for (int step = 0; step < 5000; step++) {
      // --- phase A: finish gates with LUT[last], pointwise, publish h_new ---
      int lb = g_last[b];
      const float* lrow = g_lut + (size_t)lb * 2560;
      double gate1 = G1 + (double)lrow[col1];
      double gate2 = G2 + (double)lrow[col2];
      double x1 = __shfl_xor(gate1, 4, 64);  // partner has (f,o)
      double x2 = __shfl_xor(gate2, 4, 64);
      double cn = 0.0; float hn = 0.f;
      if (c0 < 4) {
        float fi = (float)gate1, fg = (float)gate2, ff = (float)x1, fo = (float)x2;
        cn = (double)sigmf(ff) * ccur + (double)sigmf(fi) * (double)tanhf(fg);
        hn = sigmf(fo) * tanhf((float)cn);
        g_hnew[(step & 1) * 20480 + b * 640 + u0 + c0] = hn;
      }
      __syncthreads();
      if (tid == 0) bump(F1L + (bid >> 4), F1R, step);
      // --- phase B: speculative G_spec = h_new @ Wh (overlaps joint path) ---
      waitc(F1R, (u32)(step + 1) * 10u);
      const float* hb = g_hnew + (step & 1) * 20480 + b * 640;
      double a1 = 0.0, a2 = 0.0;
      for (int k = 0; k < 640; k += 4) {
        float4 h4 = *(const float4*)(hb + k);
        float4 q1 = *(const float4*)(w1 + k);
        float4 q2 = *(const float4*)(w2 + k);
        a1 += (double)h4.x * q1.x; a1 += (double)h4.y * q1.y;
        a1 += (double)h4.z * q1.z; a1 += (double)h4.w * q1.w;
        a2 += (double)h4.x * q2.x; a2 += (double)h4.y * q2.y;
        a2 += (double)h4.z * q2.z; a2 += (double)h4.w * q2.w;
      }
      // --- phase C: commit on emit ---
      waitc(F4R, (u32)(step + 1) * 2u);
      if (g_emit[b]) {
        G1 = a1; G2 = a2;
        if (c0 < 4) { ccur = cn; hcur = hn; }
      }
    }
    if (c0 < 4) {  // cache_rnn_state = stack([h, c])
      out[160000 + b * 640 + u0 + c0] = hcur;
      out[160000 + 20480 + b * 640 + u0 + c0] = (float)ccur;
    }

  } else if (bid < NGB + NPB) {
    // ========== PRED role: 4 Wpred cols each (split-k x2); p<32 also argmax ==========
    const int p = bid - NGB;  // 0..159
    const int b = tid >> 3, c2 = tid & 7;
    const int cl = c2 >> 1, half = c2 & 1;
    const int j = p * 4 + cl;
    for (int idx = tid; idx < 4 * 640; idx += 256) {
      int ci = idx / 640, k = idx - ci * 640;
      wsl[ci * LDSTR + k] = Wpred[(size_t)k * 640 + p * 4 + ci];
    }
    if (p == 32) {  // blank-column owner: Wout[:,1024] in slot 4
      for (int idx = tid; idx < 640; idx += 256)
        wsl[4 * LDSTR + idx] = Wout[(size_t)idx * 1025 + 1024];
    }
    __syncthreads();
    const int len_r = (p < 32) ? lens[p] : 0;
    int alive = (p < 32 && 0 < len_r) ? 1 : 0;
    const double bo1024 = (double)b_out[1024];
    int t = 0, s = 0;

    for (int step = 0; step < 5000; step++) {
      waitc(F1R, (u32)(step + 1) * 10u);
      const float* hb = g_hnew + (step & 1) * 20480 + b * 640 + half * 320;
      const float* wv = &wsl[cl * LDSTR + half * 320];
      double a = 0.0;
      for (int k = 0; k < 320; k += 4) {
        float4 h4 = *(const float4*)(hb + k);
        float4 q = *(const float4*)(wv + k);
        a += (double)h4.x * q.x; a += (double)h4.y * q.y;
        a += (double)h4.z * q.z; a += (double)h4.w * q.w;
      }
      a += __shfl_xor(a, 1, 64);
      if (half == 0) {
        double pre = (double)g_encT[(size_t)t * 20480 + b * 640 + j] + a;
        g_tnh[b * 640 + j] = tanhf((float)pre);
      }
      __syncthreads();
      if (tid == 0) bump(F2L + (p >> 4), F2R, step);

      if (p == 32) {  // blank logit: 8 lanes x 80 k per row
        waitc(F2R, (u32)(step + 1) * 10u);
        const float* tb = g_tnh + b * 640 + c2 * 80;
        const float* wv2 = &wsl[4 * LDSTR + c2 * 80];
        double a2 = 0.0;
        for (int k = 0; k < 80; k += 4) {
          float4 t4 = *(const float4*)(tb + k);
          float4 q = *(const float4*)(wv2 + k);
          a2 += (double)t4.x * q.x; a2 += (double)t4.y * q.y;
          a2 += (double)t4.z * q.z; a2 += (double)t4.w * q.w;
        }
        a2 += __shfl_xor(a2, 1, 64);
        a2 += __shfl_xor(a2, 2, 64);
        a2 += __shfl_xor(a2, 4, 64);
        if (c2 == 0) { g_cval[b * 132 + 128] = a2 + bo1024; g_cidx[b * 132 + 128] = 1024; }
        __syncthreads();
        if (tid == 0) {
          __builtin_amdgcn_fence(__ATOMIC_RELEASE, "agent");
          __hip_atomic_fetch_add(&g_cnt[F3R * 32], 1u, __ATOMIC_RELAXED, __HIP_MEMORY_SCOPE_AGENT);
        }
      }

      if (p < 32) {  // per-row argmax over 129 candidates, tie -> smaller index
        waitc(F3R, (u32)(step + 1) * 9u);
        sval[tid] = (tid < 129) ? g_cval[p * 132 + tid] : -1.0e300;
        sidx[tid] = (tid < 129) ? g_cidx[p * 132 + tid] : 0x7fffffff;
        __syncthreads();
        for (int off = 128; off > 0; off >>= 1) {
          if (tid < off) {
            double v2 = sval[tid + off]; int i2 = sidx[tid + off];
            if (v2 > sval[tid] || (v2 == sval[tid] && i2 < sidx[tid])) { sval[tid] = v2; sidx[tid] = i2; }
          }
          __syncthreads();
        }
        if (tid == 0) {
          int sym = sidx[0];
          int em = (alive && sym != 1024) ? 1 : 0;
          out[(size_t)p * 5000 + step] = (float)(em ? sym : 1024);
          if (em) g_last[p] = sym;
          g_emit[p] = em;
          alive = (s == 4) ? ((t + 1 < len_r) ? 1 : 0) : em;
          bump(F4L + (p >> 4), F4R, step);
        }
      }
      s++; if (s == 5) { s = 0; t++; }
    }

  } else {
    // ================= OUT role: 8 Wout cols each ==================================
    const int o = bid - NGB - NPB;  // 0..127
    const int b = tid >> 3, c = tid & 7;
    const int col = o * 8 + c;  // <= 1023
    for (int idx = tid; idx < 8 * 640; idx += 256) {
      int ci = idx / 640, k = idx - ci * 640;
      wsl[ci * LDSTR + k] = Wout[(size_t)k * 1025 + o * 8 + ci];
    }
    __syncthreads();
    const double bo = (double)b_out[col];
    const float* wv = &wsl[c * LDSTR];

    for (int step = 0; step < 5000; step++) {
      waitc(F2R, (u32)(step + 1) * 10u);
      const float* tb = g_tnh + b * 640;
      double a = bo;
      for (int k = 0; k < 640; k += 4) {
        float4 t4 = *(const float4*)(tb + k);
        float4 q = *(const float4*)(wv + k);
        a += (double)t4.x * q.x; a += (double)t4.y * q.y;
        a += (double)t4.z * q.z; a += (double)t4.w * q.w;
      }
      double bv = a; int bi = col;
#pragma unroll
      for (int m = 1; m < 8; m <<= 1) {  // argmax over the 8 cols of this block
        double v2 = __shfl_xor(bv, m, 64);
        int i2 = __shfl_xor(bi, m, 64);
        if (v2 > bv || (v2 == bv && i2 < bi)) { bv = v2; bi = i2; }
      }
      if (c == 0) { g_cval[b * 132 + o] = bv; g_cidx[b * 132 + o] = bi; }
      __syncthreads();
      if (tid == 0) bump(F3L + (o >> 4), F3R, step);
    }
  }
}

extern "C" void kernel_launch(void* const* d_in, const int* in_sizes, int n_in,
                              void* d_out, int out_size, void* d_ws, size_t ws_size,
                              hipStream_t stream) {
  const float* enc = (const float*)d_in[0];
  const int* lens = (const int*)d_in[1];
  const float* embed = (const float*)d_in[2];
  const float* Wx = (const float*)d_in[3];
  const float* Wh = (const float*)d_in[4];
  const float* b_lstm = (const float*)d_in[5];
  const float* Wenc = (const float*)d_in[6];
  const float* Wpred = (const float*)d_in[7];
  const float* b_joint = (const float*)d_in[8];
  const float* Wout = (const float*)d_in[9];
  const float* b_out = (const float*)d_in[10];
  float* out = (float*)d_out;
  (void)d_ws; (void)ws_size; (void)in_sizes; (void)n_in;

  hipLaunchKernelGGL(k_lut, dim3(1290), dim3(256), 0, stream, embed, Wx, b_lstm);
  hipLaunchKernelGGL(k_encproj, dim3(160, 32), dim3(256), 0, stream, enc, Wenc, b_joint);
  hipLaunchKernelGGL(k_decode, dim3(NBLK), dim3(256), 0, stream,
                     out, lens, Wh, Wpred, Wout, b_out);
}